// Round 4
// baseline (21.353 us; speedup 1.0000x reference)
//
#include <hip/hip_runtime.h>

// MLS rigid deformation, fused single-pass complex form.
//
// Per pixel v: w_n = 1/(|p_n - v|^2 + 1e-9)
//   pstar = (sum w p)/sw, qstar = (sum w q)/sw, vp = v - pstar
//   S = sum_n w_n q_n conj(p_n) - (sum w q) conj(sum w p)/sw
//   frv = vp * S;  out = |vp| * frv/|frv| + qstar
//
// u-trick: with u0 = w*qx, u1 = w*qy:
//   sqx = sum u0, sqy = sum u1
//   sre = sum u0*px + u1*py   (= sum w Re(q conj p))
//   sim = sum u1*px - u0*py   (= sum w Im(q conj p))
// -> only {px,py,qx,qy} needed per point, all from s_load (scalar pipe),
//    15 VALU + 1 rcp per pixel-point, <=1 SGPR operand per instr.
//
// 1 pixel/thread: 2304 blocks x 256 thr = 9216 waves = 9/SIMD for latency
// hiding (rounds 2-3 stalled at 3-4.5 waves/SIMD).

#define IMG_H 768
#define IMG_W 768
#define NPTS 64

__global__ __launch_bounds__(256, 8) void mls_main(
    const float* __restrict__ pi,
    const float* __restrict__ qi,
    float* __restrict__ out)
{
    const int idx = blockIdx.x * 256 + threadIdx.x;
    const int x = idx % IMG_W;
    const int y = idx / IMG_W;
    const float vx = (float)x;
    const float vy = (float)y;

    float sw = 0.f, spx = 0.f, spy = 0.f;
    float sqx = 0.f, sqy = 0.f, sre = 0.f, sim = 0.f;

    #pragma unroll
    for (int n = 0; n < NPTS; ++n) {
        // Uniform addresses -> s_load into SGPRs (merged to s_load_dwordx16).
        const float px = pi[2 * n + 0];
        const float py = pi[2 * n + 1];
        const float qx = qi[2 * n + 0];
        const float qy = qi[2 * n + 1];

        const float dx = px - vx;
        const float dy = py - vy;
        const float t  = fmaf(dy, dy, 1e-9f);
        const float d0 = fmaf(dx, dx, t);
        const float w  = __builtin_amdgcn_rcpf(d0);

        const float u0 = w * qx;
        const float u1 = w * qy;
        sw  += w;
        spx = fmaf(w,  px, spx);
        spy = fmaf(w,  py, spy);
        sqx += u0;
        sqy += u1;
        sre = fmaf(u0, px, sre);
        sre = fmaf(u1, py, sre);
        sim = fmaf(u1, px, sim);
        sim = fmaf(-u0, py, sim);
    }

    const float rsw = __builtin_amdgcn_rcpf(sw);
    const float psx = spx * rsw, psy = spy * rsw;   // pstar
    const float qsx = sqx * rsw, qsy = sqy * rsw;   // qstar
    // S = (sre,sim) - swq * conj(swp) / sw
    const float cre = fmaf(sqx, spx, sqy * spy) * rsw;
    const float cim = fmaf(sqy, spx, -sqx * spy) * rsw;
    const float Sre = sre - cre;
    const float Sim = sim - cim;
    const float vpx = vx - psx;
    const float vpy = vy - psy;
    const float frx = fmaf(vpx, Sre, -vpy * Sim);
    const float fry = fmaf(vpx, Sim, vpy * Sre);
    const float vpn = sqrtf(fmaf(vpx, vpx, vpy * vpy));
    const float frn = sqrtf(fmaf(frx, frx, fry * fry)) + 1e-10f;
    const float s = vpn * __builtin_amdgcn_rcpf(frn);

    ((float2*)out)[idx] = make_float2(fmaf(s, frx, qsx), fmaf(s, fry, qsy));
}

extern "C" void kernel_launch(void* const* d_in, const int* in_sizes, int n_in,
                              void* d_out, int out_size, void* d_ws, size_t ws_size,
                              hipStream_t stream) {
    // d_in[0] = img (unused), d_in[1] = pi (64,2) f32, d_in[2] = qi (64,2) f32
    const float* pi = (const float*)d_in[1];
    const float* qi = (const float*)d_in[2];
    float* out = (float*)d_out;

    const int npix = IMG_H * IMG_W;               // 589824
    mls_main<<<npix / 256, 256, 0, stream>>>(pi, qi, out);
}

// Round 5
// 19.412 us; speedup vs baseline: 1.1000x; 1.1000x over previous
//
#include <hip/hip_runtime.h>

// MLS rigid deformation, fused single-pass complex form, packed-FP32 inner loop.
//
// Per pixel v: w_n = 1/(|p_n - v|^2 + 1e-9)
//   pstar = (sum w p)/sw, qstar = (sum w q)/sw, vp = v - pstar
//   S = sum_n w_n q_n conj(p_n) - (sum w q) conj(sum w p)/sw
//   frv = vp * S;  out = |vp| * frv/|frv| + qstar
//
// Packed form: u = w*{qx,qy} (pk_mul); A += u*px, C += u*py (pk_fma) give
//   sre = A.x + C.y, sim = A.y - C.x  (no swap/neg shuffles in the loop).
// {d0,d1} = {dx,dx-1}^2 + {t,t} shares dy,t across 2 adjacent pixels.
// ~8.5 VALU slots + 1 rcp per pixel-point, mostly v_pk_* (2 FLOPs/slot).
//
// Rounds 3/4 showed issue-bound behavior (3 vs 9 waves/SIMD: same
// time-per-slot), so this targets slot count, not occupancy.

typedef float f2 __attribute__((ext_vector_type(2)));

#define IMG_H 768
#define IMG_W 768
#define NPTS 64

__device__ __forceinline__ float2 mls_finish(
    float vxk, float vy, float sw,
    f2 sp, f2 sq, float sre, float sim)
{
    const float rsw = __builtin_amdgcn_rcpf(sw);
    const float psx = sp.x * rsw, psy = sp.y * rsw;   // pstar
    const float qsx = sq.x * rsw, qsy = sq.y * rsw;   // qstar
    // S = (sre,sim) - swq * conj(swp) / sw
    const float cre = fmaf(sq.x, sp.x, sq.y * sp.y) * rsw;
    const float cim = fmaf(sq.y, sp.x, -sq.x * sp.y) * rsw;
    const float Sre = sre - cre;
    const float Sim = sim - cim;
    const float vpx = vxk - psx;
    const float vpy = vy - psy;
    const float frx = fmaf(vpx, Sre, -vpy * Sim);
    const float fry = fmaf(vpx, Sim, vpy * Sre);
    const float vpn = sqrtf(fmaf(vpx, vpx, vpy * vpy));
    const float frn = sqrtf(fmaf(frx, frx, fry * fry)) + 1e-10f;
    const float s = vpn * __builtin_amdgcn_rcpf(frn);
    return make_float2(fmaf(s, frx, qsx), fmaf(s, fry, qsy));
}

__global__ __launch_bounds__(128) void mls_main(
    const float* __restrict__ pi,
    const float* __restrict__ qi,
    float* __restrict__ out)
{
    const int idx = blockIdx.x * 128 + threadIdx.x;   // one thread = 2 pixels
    const int xh = idx % (IMG_W / 2);
    const int y  = idx / (IMG_W / 2);
    const float vx = (float)(2 * xh);
    const float vy = (float)y;

    f2 sw2 = {0.f, 0.f};                               // {sw(px0), sw(px1)}
    f2 sp0 = {0.f, 0.f}, sq0 = {0.f, 0.f}, A0 = {0.f, 0.f}, C0 = {0.f, 0.f};
    f2 sp1 = {0.f, 0.f}, sq1 = {0.f, 0.f}, A1 = {0.f, 0.f}, C1 = {0.f, 0.f};

    #pragma unroll
    for (int n = 0; n < NPTS; ++n) {
        // Uniform addresses -> scalar (s_load) operands.
        const float px = pi[2 * n + 0];
        const float py = pi[2 * n + 1];
        const float qx = qi[2 * n + 0];
        const float qy = qi[2 * n + 1];
        const f2 ppk = {px, py};
        const f2 qpk = {qx, qy};

        const float dx = px - vx;
        const float dy = py - vy;
        const float t  = fmaf(dy, dy, 1e-9f);
        const f2 dd  = {dx, dx - 1.f};
        const f2 d01 = dd * dd + (f2){t, t};           // {|p-v0|^2, |p-v1|^2}
        const float w0 = __builtin_amdgcn_rcpf(d01.x);
        const float w1 = __builtin_amdgcn_rcpf(d01.y);

        sw2 += (f2){w0, w1};
        sp0 += w0 * ppk;          sp1 += w1 * ppk;
        const f2 u0 = w0 * qpk;   const f2 u1 = w1 * qpk;
        sq0 += u0;                sq1 += u1;
        A0 += u0 * px;            A1 += u1 * px;
        C0 += u0 * py;            C1 += u1 * py;
    }

    const float2 r0 = mls_finish(vx,       vy, sw2.x, sp0, sq0, A0.x + C0.y, A0.y - C0.x);
    const float2 r1 = mls_finish(vx + 1.f, vy, sw2.y, sp1, sq1, A1.x + C1.y, A1.y - C1.x);

    ((float4*)out)[idx] = make_float4(r0.x, r0.y, r1.x, r1.y);
}

extern "C" void kernel_launch(void* const* d_in, const int* in_sizes, int n_in,
                              void* d_out, int out_size, void* d_ws, size_t ws_size,
                              hipStream_t stream) {
    // d_in[0] = img (unused), d_in[1] = pi (64,2) f32, d_in[2] = qi (64,2) f32
    const float* pi = (const float*)d_in[1];
    const float* qi = (const float*)d_in[2];
    float* out = (float*)d_out;

    const int nthreads = IMG_H * (IMG_W / 2);          // 294912
    mls_main<<<nthreads / 128, 128, 0, stream>>>(pi, qi, out);  // 2304 blocks = 9/CU exact
}